// Round 10
// baseline (60.034 us; speedup 1.0000x reference)
//
#include <hip/hip_runtime.h>
#include <math.h>

#define NROW 2048
#define BITS 64
#define MB 512             /* main-kernel threads (8 waves) */
#define RPB 8              /* rows per block */
#define JQ 2               /* consecutive j's per thread */
#define NRG (NROW / RPB)   /* 256 row-groups */
#define NSL 2              /* j slices */
#define JSL (NROW / NSL)   /* 1024 j per slice */
#define MAXPOS 128         /* >= max label count (64 +- 8, 8 sigma) */

#define LN2_F   0.6931471805599453f
#define THSCALE 0.7213475204444817f      /* 0.5 * log2(e) */
#define A_SC    7.213475204444817f       /* 5.0 * log2(e) */

// ---------------------------------------------------------------------------
// K1: blocks 0..31 transpose b -> bT[k][j]; block 32 counting-sorts rows by
// label: offG[33] exclusive offsets + idxG[2048] row indices (ascending j
// within each label -- fixes the positive-pairing order deterministically).
// ---------------------------------------------------------------------------
__global__ __launch_bounds__(256) void prep_kernel(
    const float* __restrict__ b, const int* __restrict__ y,
    float* __restrict__ bT, int* __restrict__ offG, int* __restrict__ idxG)
{
    union U {
        float tile[64][65];
        struct { int ys[NROW]; int hist[32]; int offL[33]; } s;
    };
    __shared__ U u;
    const int t = threadIdx.x;

    if (blockIdx.x < 32) {
        const int j0 = blockIdx.x * 64;
        {
            const int jj = t >> 2, q = t & 3;
            const float4* b4 = reinterpret_cast<const float4*>(b + (size_t)(j0 + jj) * BITS);
#pragma unroll
            for (int m = 0; m < 4; ++m) {
                const float4 v = b4[q * 4 + m];
                const int col = q * 16 + m * 4;
                u.tile[jj][col + 0] = v.x; u.tile[jj][col + 1] = v.y;
                u.tile[jj][col + 2] = v.z; u.tile[jj][col + 3] = v.w;
            }
        }
        __syncthreads();
        {
            const int k = t >> 2, q = t & 3;
#pragma unroll
            for (int s = 0; s < 4; ++s) {
                float4 v;
                v.x = u.tile[q * 16 + s * 4 + 0][k];
                v.y = u.tile[q * 16 + s * 4 + 1][k];
                v.z = u.tile[q * 16 + s * 4 + 2][k];
                v.w = u.tile[q * 16 + s * 4 + 3][k];
                *reinterpret_cast<float4*>(&bT[(size_t)k * NROW + j0 + q * 16 + s * 4]) = v;
            }
        }
        return;
    }

    // ---- block 32: counting sort of y ----
    for (int k = t; k < NROW; k += 256) u.s.ys[k] = y[k];
    if (t < 32) u.s.hist[t] = 0;
    __syncthreads();
    for (int k = t; k < NROW; k += 256) atomicAdd(&u.s.hist[u.s.ys[k]], 1);
    __syncthreads();
    const int w = t >> 6, lane = t & 63;
    if (w == 0) {
        int v = (lane < 32) ? u.s.hist[lane] : 0;
#pragma unroll
        for (int off = 1; off < 32; off <<= 1) {
            const int tv = __shfl_up(v, off);
            if (lane >= off) v += tv;
        }
        if (lane < 32) { u.s.offL[lane + 1] = v; offG[lane + 1] = v; }
        if (lane == 0) { u.s.offL[0] = 0; offG[0] = 0; }
    }
    __syncthreads();
    // scatter: wave w handles labels w*8 .. w*8+7 (ascending j order)
    const unsigned long long lm = (1ull << lane) - 1ull;
    for (int s8 = 0; s8 < 8; ++s8) {
        const int lab = w * 8 + s8;
        int base = u.s.offL[lab];
        for (int c = 0; c < NROW / 64; ++c) {
            const int j = c * 64 + lane;
            const bool f = (u.s.ys[j] == lab);
            const unsigned long long mp = __ballot(f);
            if (f) idxG[base + (int)__popcll(mp & lm)] = j;
            base += (int)__popcll(mp);
        }
    }
}

// ---------------------------------------------------------------------------
// K2: per row i, compute pe[p] = exp2(-theta'(i, jp)) for all P positives
// (jp from idxG, ascending), zero-pad to MAXPOS. One wave per row.
// ---------------------------------------------------------------------------
__global__ __launch_bounds__(256) void pos_kernel(
    const float* __restrict__ b, const int* __restrict__ y,
    const int* __restrict__ offG, const int* __restrict__ idxG,
    float* __restrict__ posPeG)
{
    __shared__ __align__(16) float biS[4][BITS];
    const int t = threadIdx.x, w = t >> 6, lane = t & 63;
    const int i = blockIdx.x * 4 + w;
    if (lane < BITS) biS[w][lane] = b[(size_t)i * BITS + lane];
    __syncthreads();
    const int yi = y[i];
    const int st = offG[yi];
    const int P  = offG[yi + 1] - st;
    const float4* bi4 = reinterpret_cast<const float4*>(&biS[w][0]);
    for (int p = lane; p < MAXPOS; p += 64) {
        float val = 0.f;
        if (p < P) {
            const int jp = idxG[st + p];
            const float4* rp = reinterpret_cast<const float4*>(b + (size_t)jp * BITS);
            float acc = 0.f;
#pragma unroll
            for (int k4 = 0; k4 < BITS / 4; ++k4) {
                const float4 a = bi4[k4], v = rp[k4];
                acc += a.x * v.x + a.y * v.y + a.z * v.z + a.w * v.w;
            }
            val = __builtin_amdgcn_exp2f(-THSCALE * acc);
        }
        posPeG[(size_t)i * MAXPOS + p] = val;
    }
}

// ---------------------------------------------------------------------------
// K3 (main): grid (256 row-groups, 2 j-slices) x 512 threads (2 blocks/CU).
//   No compaction: positives arrive pre-exp'd; (s,m) = (p0+p1, p0*p1) per
//   positive-pair staged once into 4KB LDS.
//   Thread owns j = slice*1024 + 2t, +1: coalesced float2 bT loads,
//   biT[k][0..7] broadcast -> 16 FMAs per k.
//   e = (y_j == y_r) ? 0 : exp2(th' + alpha')  -- pos x pos => log2(1) = 0.
//   Pair loop: 2 pairs per log: log2(fma(e^2, m, fma(e, s, 1))), exact,
//   overflow-safe (>= 8 sigma). loss2 partial from slice-0 blocks.
// ---------------------------------------------------------------------------
__global__ __launch_bounds__(MB) void dhn_main(
    const float* __restrict__ b, const float* __restrict__ bT,
    const int* __restrict__ y, const int* __restrict__ offG,
    const float* __restrict__ posPeG,
    float* __restrict__ blockLoss, float* __restrict__ blockQ)
{
    const int rg    = blockIdx.x;
    const int slice = blockIdx.y;
    const int i0    = rg * RPB;
    const int tid   = threadIdx.x;
    const int w = tid >> 6, lane = tid & 63;

    __shared__ __align__(16) float  biT[BITS * RPB];     /* [k][r] */
    __shared__ __align__(16) float2 posSM[RPB][MAXPOS / 2];
    __shared__ float wred[MB / 64], wq[MB / 64];

    // stage biT (k = tid>>3, r = tid&7)
    biT[tid] = b[(size_t)(i0 + (tid & 7)) * BITS + (tid >> 3)];
    // stage posSM: wave w -> row w; lane -> pair pp
    {
        const float2 pg = reinterpret_cast<const float2*>(posPeG)
                              [(size_t)(i0 + w) * (MAXPOS / 2) + lane];
        posSM[w][lane] = make_float2(pg.x + pg.y, pg.x * pg.y);
    }
    __syncthreads();

    // ---- dot phase ----
    float th[JQ][RPB] = {};
    {
        const float2* bt2 = reinterpret_cast<const float2*>(bT);
        const float4* bi4 = reinterpret_cast<const float4*>(biT);
        const int jb = slice * (JSL / 2) + tid;
#pragma unroll 8
        for (int k = 0; k < BITS; ++k) {
            const float2 bj = bt2[k * (NROW / 2) + jb];
            const float4 bA = bi4[k * 2 + 0];
            const float4 bB = bi4[k * 2 + 1];
            th[0][0] += bj.x * bA.x; th[0][1] += bj.x * bA.y;
            th[0][2] += bj.x * bA.z; th[0][3] += bj.x * bA.w;
            th[0][4] += bj.x * bB.x; th[0][5] += bj.x * bB.y;
            th[0][6] += bj.x * bB.z; th[0][7] += bj.x * bB.w;
            th[1][0] += bj.y * bA.x; th[1][1] += bj.y * bA.y;
            th[1][2] += bj.y * bA.z; th[1][3] += bj.y * bA.w;
            th[1][4] += bj.y * bB.x; th[1][5] += bj.y * bB.y;
            th[1][6] += bj.y * bB.z; th[1][7] += bj.y * bB.w;
        }
    }
    const int2 y2 = reinterpret_cast<const int2*>(y)[slice * (JSL / 2) + tid];

    // ---- per-row pair loops ----
    float total = 0.f;
#pragma unroll
    for (int r = 0; r < RPB; ++r) {
        const int yr = y[i0 + r];
        const int P  = offG[yr + 1] - offG[yr];
        const int PG = ((P + 7) & ~7) >> 3;          /* groups of 8 positives */
        const float x0 = __builtin_amdgcn_exp2f(th[0][r] * THSCALE + A_SC);
        const float x1 = __builtin_amdgcn_exp2f(th[1][r] * THSCALE + A_SC);
        const float e0 = (y2.x == yr) ? 0.f : x0;
        const float e1 = (y2.y == yr) ? 0.f : x1;
        const float e20 = e0 * e0, e21 = e1 * e1;
        float la0 = 0.f, la1 = 0.f;
        const float4* sm4 = reinterpret_cast<const float4*>(&posSM[r][0]);
        for (int g = 0; g < PG; ++g) {
            const float4 A = sm4[2 * g + 0];   /* s0 m0 s1 m1 */
            const float4 B = sm4[2 * g + 1];   /* s2 m2 s3 m3 */
            la0 += (__builtin_amdgcn_logf(fmaf(e20, A.y, fmaf(e0, A.x, 1.f)))
                  + __builtin_amdgcn_logf(fmaf(e20, A.w, fmaf(e0, A.z, 1.f))))
                 + (__builtin_amdgcn_logf(fmaf(e20, B.y, fmaf(e0, B.x, 1.f)))
                  + __builtin_amdgcn_logf(fmaf(e20, B.w, fmaf(e0, B.z, 1.f))));
            la1 += (__builtin_amdgcn_logf(fmaf(e21, A.y, fmaf(e1, A.x, 1.f)))
                  + __builtin_amdgcn_logf(fmaf(e21, A.w, fmaf(e1, A.z, 1.f))))
                 + (__builtin_amdgcn_logf(fmaf(e21, B.y, fmaf(e1, B.x, 1.f)))
                  + __builtin_amdgcn_logf(fmaf(e21, B.w, fmaf(e1, B.z, 1.f))));
        }
        if (P < NROW) {
            const float denom = (float)P * (float)(NROW - P);
            total += (la0 + la1) / denom;
        }
    }
    total *= LN2_F;

    // ---- loss2 partial (slice 0 only; 8 rows x 64 staged in biT) ----
    float q2 = 0.f;
    if (slice == 0) {
        const float x  = biT[tid];
        const float sg = (x > 0.f) ? 1.f : ((x < 0.f) ? -1.f : 0.f);
        const float d  = x - sg;
        q2 = d * d;
    }

    // ---- reductions ----
#pragma unroll
    for (int off = 32; off > 0; off >>= 1) {
        total += __shfl_xor(total, off);
        q2    += __shfl_xor(q2, off);
    }
    if (lane == 0) { wred[w] = total; wq[w] = q2; }
    __syncthreads();
    if (tid == 0) {
        float tl = 0.f, tq = 0.f;
#pragma unroll
        for (int v = 0; v < MB / 64; ++v) { tl += wred[v]; tq += wq[v]; }
        blockLoss[slice * NRG + rg] = tl;
        if (slice == 0) blockQ[rg] = tq;
    }
}

// ---------------------------------------------------------------------------
// K4: final reduce -> 3 outputs (cnt recomputed from offG/y)
// ---------------------------------------------------------------------------
__global__ __launch_bounds__(256) void dhn_final_kernel(
    const int* __restrict__ y, const int* __restrict__ offG,
    const float* __restrict__ blockLoss, const float* __restrict__ blockQ,
    float* __restrict__ out)
{
    const int tid = threadIdx.x;
    const int w = tid >> 6, lane = tid & 63;
    __shared__ float r1[4], r2[4], r3[4];

    float sl = 0.f, sv = 0.f, sq = 0.f;
    for (int i = tid; i < NSL * NRG; i += 256) sl += blockLoss[i];
    for (int i = tid; i < NRG; i += 256) sq += blockQ[i];
    for (int i = tid; i < NROW; i += 256) {
        const int yi = y[i];
        const int P = offG[yi + 1] - offG[yi];
        sv += ((P > 0) && (P < NROW)) ? 1.f : 0.f;
    }
#pragma unroll
    for (int off = 32; off > 0; off >>= 1) {
        sl += __shfl_xor(sl, off);
        sv += __shfl_xor(sv, off);
        sq += __shfl_xor(sq, off);
    }
    if (lane == 0) { r1[w] = sl; r2[w] = sv; r3[w] = sq; }
    __syncthreads();
    if (tid == 0) {
        float SL = 0.f, SV = 0.f, SQ = 0.f;
#pragma unroll
        for (int v = 0; v < 4; ++v) { SL += r1[v]; SV += r2[v]; SQ += r3[v]; }
        const float loss1 = (SV > 0.f) ? SL / fmaxf(SV, 1.f) : 0.f;
        const float loss2 = SQ / (float)(NROW * BITS);
        out[0] = loss1 + 1.0f * loss2;   /* LAMBDA = 1.0 */
        out[1] = loss1;
        out[2] = loss2;
    }
}

extern "C" void kernel_launch(void* const* d_in, const int* in_sizes, int n_in,
                              void* d_out, int out_size, void* d_ws, size_t ws_size,
                              hipStream_t stream) {
    const float* b = (const float*)d_in[0];
    const int*   y = (const int*)d_in[1];
    float* out = (float*)d_out;

    /* workspace layout (needs ~1.6 MB; harness provides >= 16 MB) */
    int*   offG      = (int*)d_ws;                                   /* [33]        */
    int*   idxG      = (int*)((char*)d_ws + 1024);                   /* [2048]      */
    float* blockLoss = (float*)((char*)d_ws + 10240);                /* [512]       */
    float* blockQ    = (float*)((char*)d_ws + 12800);                /* [256]       */
    float* posPeG    = (float*)((char*)d_ws + 16384);                /* [2048*128]  */
    float* bT        = (float*)((char*)d_ws + 16384 + 1048576);      /* [64*2048]   */

    prep_kernel<<<33, 256, 0, stream>>>(b, y, bT, offG, idxG);
    pos_kernel<<<NROW / 4, 256, 0, stream>>>(b, y, offG, idxG, posPeG);
    dhn_main<<<dim3(NRG, NSL), MB, 0, stream>>>(b, bT, y, offG, posPeG,
                                                blockLoss, blockQ);
    dhn_final_kernel<<<1, 256, 0, stream>>>(y, offG, blockLoss, blockQ, out);
}

// Round 11
// 42.334 us; speedup vs baseline: 1.4181x; 1.4181x over previous
//
#include <hip/hip_runtime.h>
#include <math.h>

#define NROW 2048
#define BITS 64
#define MB 512             /* main-kernel threads (8 waves) */
#define RPB 4              /* rows per block */
#define JQ 4               /* consecutive j's per thread */
#define NBLK (NROW / RPB)  /* 512 main blocks */
#define NWV (MB / 64)      /* 8 waves */
#define MAXPOS 256

#define LN2_F   0.6931471805599453f
#define THSCALE 0.7213475204444817f      /* 0.5 * log2(e) */
#define A_SC    7.213475204444817f       /* 5.0 * log2(e) */

// ---------------------------------------------------------------------------
// Kernel 0: bT[k][j] = b[j][k]   (64-row tiles)
// ---------------------------------------------------------------------------
__global__ __launch_bounds__(256) void bt_kernel(const float* __restrict__ b,
                                                 float* __restrict__ bT)
{
    __shared__ float tile[64][65];
    const int t  = threadIdx.x;
    const int j0 = blockIdx.x * 64;
    {
        const int jj = t >> 2, q = t & 3;
        const float4* b4 = reinterpret_cast<const float4*>(b + (size_t)(j0 + jj) * BITS);
#pragma unroll
        for (int m = 0; m < 4; ++m) {
            const float4 v = b4[q * 4 + m];
            const int col = q * 16 + m * 4;
            tile[jj][col + 0] = v.x; tile[jj][col + 1] = v.y;
            tile[jj][col + 2] = v.z; tile[jj][col + 3] = v.w;
        }
    }
    __syncthreads();
    {
        const int k = t >> 2, q = t & 3;
#pragma unroll
        for (int s = 0; s < 4; ++s) {
            float4 v;
            v.x = tile[q * 16 + s * 4 + 0][k];
            v.y = tile[q * 16 + s * 4 + 1][k];
            v.z = tile[q * 16 + s * 4 + 2][k];
            v.w = tile[q * 16 + s * 4 + 3][k];
            *reinterpret_cast<float4*>(&bT[(size_t)k * NROW + j0 + q * 16 + s * 4]) = v;
        }
    }
}

// exact per-quad fallback (used only when the Horner product overflows f32)
__device__ __forceinline__ float slow4(float e, const float* __restrict__ pp)
{
    float s = 0.f;
#pragma unroll
    for (int k = 0; k < 4; ++k)
        s += __builtin_amdgcn_logf(fmaf(e, pp[k], 1.f));
    return s;
}

// ---------------------------------------------------------------------------
// Kernel 1 (fused, round-8 structure): 512 blocks x 512 threads, 4 rows/block.
//   Thread t owns j = 4t..4t+3 (one float4 bT load; biT[k] b128 broadcast).
//   ev = exp2(pos ? -th' : th'+alpha'); En=0 for positives => pos x pos pairs
//   contribute log2(1)=0 exactly.
//   NEW: positives expanded into elementary symmetric polys per quad:
//     (c1..c4) of (1+p0 x)(1+p1 x)(1+p2 x)(1+p3 x), staged once in LDS.
//   Pair loop: Horner h = (((c4 e + c3)e + c2)e + c1)e + 1 = prod(1+e p_k)
//     -> 4 fma + 1 log per 4 pairs (log2 is quarter-rate: trans count rules).
//   Rare overflow (~4e3/dispatch, 3.84 sigma): isinf(h) -> exact slow4 path.
// ---------------------------------------------------------------------------
template <bool TR>
__global__ __launch_bounds__(MB) void dhn_main(
    const float* __restrict__ b, const float* __restrict__ bT,
    const int* __restrict__ y,
    float* __restrict__ blockLoss, float* __restrict__ blockValid,
    float* __restrict__ blockQ)
{
    const int br  = blockIdx.x;
    const int i0  = br * RPB;
    const int tid = threadIdx.x;
    const int w = tid >> 6, lane = tid & 63;

    __shared__ __align__(16) float  biT[BITS * RPB];          /* [k][r] */
    __shared__ __align__(16) float  posPe[RPB][MAXPOS + 8];
    __shared__ __align__(16) float4 posSG[RPB][MAXPOS / 4 + 2];
    __shared__ int   waveTot[RPB][NWV];
    __shared__ int   waveBase[RPB][NWV];
    __shared__ int   pcnt[RPB];
    __shared__ float wred[NWV], wq[NWV];

    if (tid < BITS * RPB) {
        const int k = tid >> 2, r = tid & 3;
        biT[tid] = b[(size_t)(i0 + r) * BITS + k];
    }
    __syncthreads();

    // ---- dot phase: th[q][r] for j = 4*tid + q ----
    float th[JQ][RPB] = {};
    if constexpr (TR) {
        const float4* bt4 = reinterpret_cast<const float4*>(bT);
        const float4* bi4 = reinterpret_cast<const float4*>(biT);
#pragma unroll 8
        for (int k = 0; k < BITS; ++k) {
            const float4 bj = bt4[k * (NROW / 4) + tid];
            const float4 bi = bi4[k];
            th[0][0] += bj.x * bi.x; th[0][1] += bj.x * bi.y;
            th[0][2] += bj.x * bi.z; th[0][3] += bj.x * bi.w;
            th[1][0] += bj.y * bi.x; th[1][1] += bj.y * bi.y;
            th[1][2] += bj.y * bi.z; th[1][3] += bj.y * bi.w;
            th[2][0] += bj.z * bi.x; th[2][1] += bj.z * bi.y;
            th[2][2] += bj.z * bi.z; th[2][3] += bj.z * bi.w;
            th[3][0] += bj.w * bi.x; th[3][1] += bj.w * bi.y;
            th[3][2] += bj.w * bi.z; th[3][3] += bj.w * bi.w;
        }
    } else {
        for (int k = 0; k < BITS; ++k) {
#pragma unroll
            for (int q = 0; q < JQ; ++q) {
                const float v = b[(size_t)(4 * tid + q) * BITS + k];
#pragma unroll
                for (int r = 0; r < RPB; ++r) th[q][r] += v * biT[k * 4 + r];
            }
        }
    }

    const int4 y4 = reinterpret_cast<const int4*>(y)[tid];
    const int yj[JQ] = { y4.x, y4.y, y4.z, y4.w };
    int yr[RPB];
#pragma unroll
    for (int r = 0; r < RPB; ++r) yr[r] = y[i0 + r];

    // ---- exp2 + masks ----
    float ev[JQ][RPB];
    int pm[RPB], cnt[RPB];
#pragma unroll
    for (int r = 0; r < RPB; ++r) {
        int m = 0;
#pragma unroll
        for (int q = 0; q < JQ; ++q) {
            const float t2 = th[q][r] * THSCALE;
            const bool f = (yj[q] == yr[r]);
            ev[q][r] = __builtin_amdgcn_exp2f(f ? -t2 : t2 + A_SC);
            if (f) m |= 1 << q;
        }
        pm[r] = m;
        cnt[r] = __popc(m);
    }

    // ---- prefix scan of positive counts (per row) ----
    int excl[RPB];
#pragma unroll
    for (int r = 0; r < RPB; ++r) {
        int v = cnt[r];
#pragma unroll
        for (int off = 1; off < 64; off <<= 1) {
            const int t2 = __shfl_up(v, off);
            if (lane >= off) v += t2;
        }
        excl[r] = v - cnt[r];
        if (lane == 63) waveTot[r][w] = v;
    }
    __syncthreads();
    if (tid < RPB) {
        int base = 0;
#pragma unroll
        for (int wv = 0; wv < NWV; ++wv) { waveBase[tid][wv] = base; base += waveTot[tid][wv]; }
        pcnt[tid] = base;
    }
    __syncthreads();

    // ---- scatter positives' pe; pad to multiple of 8 with zeros ----
#pragma unroll
    for (int r = 0; r < RPB; ++r) {
        int o = waveBase[r][w] + excl[r];
#pragma unroll
        for (int q = 0; q < JQ; ++q) {
            if ((pm[r] >> q) & 1) {
                if (o < MAXPOS) posPe[r][o] = ev[q][r];
                ++o;
            }
        }
    }
    if (tid < RPB * 8) {
        const int r = tid >> 3, q = tid & 7;
        const int P = pcnt[r] < MAXPOS ? pcnt[r] : MAXPOS;
        const int idx = P + q;
        if (idx < ((P + 7) & ~7)) posPe[r][idx] = 0.f;
    }
    __syncthreads();

    // ---- build symmetric-poly quads (c1..c4) once per block ----
    if (tid < RPB * (MAXPOS / 4)) {
        const int r = tid / (MAXPOS / 4);
        const int g = tid % (MAXPOS / 4);
        const int P = pcnt[r] < MAXPOS ? pcnt[r] : MAXPOS;
        const int Ppad = (P + 7) & ~7;
        if (g * 4 < Ppad) {
            float c1 = 0.f, c2 = 0.f, c3 = 0.f, c4 = 0.f;
#pragma unroll
            for (int k = 0; k < 4; ++k) {
                const float p = posPe[r][g * 4 + k];
                c4 = fmaf(p, c3, c4);
                c3 = fmaf(p, c2, c3);
                c2 = fmaf(p, c1, c2);
                c1 += p;
            }
            posSG[r][g] = make_float4(c1, c2, c3, c4);
        }
    }
    __syncthreads();

    // ---- pair loop: 2 quads (8 positives) per iteration ----
    float total = 0.f;
#pragma unroll
    for (int r = 0; r < RPB; ++r) {
        const int Pc = pcnt[r];
        const int P  = Pc < MAXPOS ? Pc : MAXPOS;
        const int PG = ((P + 7) & ~7) >> 3;          /* pairs of quads */
        float e[JQ];
#pragma unroll
        for (int q = 0; q < JQ; ++q)
            e[q] = ((pm[r] >> q) & 1) ? 0.f : ev[q][r];
        float a[JQ] = {};
        const float4* sg4 = &posSG[r][0];
        const float*  pp  = &posPe[r][0];
        for (int g = 0; g < PG; ++g) {
            const float4 A = sg4[2 * g + 0];
            const float4 B = sg4[2 * g + 1];
#pragma unroll
            for (int q = 0; q < JQ; ++q) {
                const float eq = e[q];
                const float hA = fmaf(fmaf(fmaf(fmaf(A.w, eq, A.z), eq, A.y), eq, A.x), eq, 1.f);
                float lA = __builtin_amdgcn_logf(hA);
                if (__builtin_expect(isinf(hA), 0)) lA = slow4(eq, pp + 8 * g);
                const float hB = fmaf(fmaf(fmaf(fmaf(B.w, eq, B.z), eq, B.y), eq, B.x), eq, 1.f);
                float lB = __builtin_amdgcn_logf(hB);
                if (__builtin_expect(isinf(hB), 0)) lB = slow4(eq, pp + 8 * g + 4);
                a[q] += lA + lB;
            }
        }
        const bool valid = (Pc > 0) && (Pc < NROW);
        const float denom = (float)Pc * (float)(NROW - Pc);
        total += valid ? ((a[0] + a[1]) + (a[2] + a[3])) / denom : 0.f;
    }
    total *= LN2_F;

    // ---- loss2 partial from LDS-staged rows (4 x 64 = 256 elems) ----
    float q2 = 0.f;
    if (tid < BITS * RPB) {
        const float x  = biT[tid];
        const float sg = (x > 0.f) ? 1.f : ((x < 0.f) ? -1.f : 0.f);
        const float d  = x - sg;
        q2 = d * d;
    }

    // ---- reductions ----
#pragma unroll
    for (int off = 32; off > 0; off >>= 1) {
        total += __shfl_xor(total, off);
        q2    += __shfl_xor(q2, off);
    }
    if (lane == 0) { wred[w] = total; wq[w] = q2; }
    __syncthreads();
    if (tid == 0) {
        float tl = 0.f, tq = 0.f;
#pragma unroll
        for (int v = 0; v < NWV; ++v) { tl += wred[v]; tq += wq[v]; }
        blockLoss[br] = tl;
        blockQ[br]    = tq;
        float vc = 0.f;
#pragma unroll
        for (int r = 0; r < RPB; ++r)
            vc += ((pcnt[r] > 0) && (pcnt[r] < NROW)) ? 1.f : 0.f;
        blockValid[br] = vc;
    }
}

// ---------------------------------------------------------------------------
// Kernel 2: reduce 512 block partials -> 3 outputs
// ---------------------------------------------------------------------------
__global__ __launch_bounds__(256) void dhn_final_kernel(
    const float* __restrict__ blockLoss, const float* __restrict__ blockValid,
    const float* __restrict__ blockQ, float* __restrict__ out)
{
    const int tid = threadIdx.x;
    const int w = tid >> 6, lane = tid & 63;
    __shared__ float r1[4], r2[4], r3[4];

    float sl = 0.f, sv = 0.f, sq = 0.f;
    for (int i = tid; i < NBLK; i += 256) {
        sl += blockLoss[i]; sv += blockValid[i]; sq += blockQ[i];
    }
#pragma unroll
    for (int off = 32; off > 0; off >>= 1) {
        sl += __shfl_xor(sl, off);
        sv += __shfl_xor(sv, off);
        sq += __shfl_xor(sq, off);
    }
    if (lane == 0) { r1[w] = sl; r2[w] = sv; r3[w] = sq; }
    __syncthreads();
    if (tid == 0) {
        float SL = 0.f, SV = 0.f, SQ = 0.f;
#pragma unroll
        for (int v = 0; v < 4; ++v) { SL += r1[v]; SV += r2[v]; SQ += r3[v]; }
        const float loss1 = (SV > 0.f) ? SL / fmaxf(SV, 1.f) : 0.f;
        const float loss2 = SQ / (float)(NROW * BITS);
        out[0] = loss1 + 1.0f * loss2;   /* LAMBDA = 1.0 */
        out[1] = loss1;
        out[2] = loss2;
    }
}

extern "C" void kernel_launch(void* const* d_in, const int* in_sizes, int n_in,
                              void* d_out, int out_size, void* d_ws, size_t ws_size,
                              hipStream_t stream) {
    const float* b = (const float*)d_in[0];
    const int*   y = (const int*)d_in[1];
    float* out = (float*)d_out;

    float* blockLoss  = (float*)d_ws;                      /* [512] */
    float* blockValid = (float*)((char*)d_ws + 4096);      /* [512] */
    float* blockQ     = (float*)((char*)d_ws + 8192);      /* [512] */
    float* bT         = (float*)((char*)d_ws + 16384);     /* [64*2048] */

    const size_t need = 16384 + (size_t)BITS * NROW * sizeof(float);
    if (ws_size >= need) {
        bt_kernel<<<NROW / 64, 256, 0, stream>>>(b, bT);
        dhn_main<true><<<NBLK, MB, 0, stream>>>(b, bT, y, blockLoss, blockValid, blockQ);
    } else {
        dhn_main<false><<<NBLK, MB, 0, stream>>>(b, nullptr, y, blockLoss, blockValid, blockQ);
    }
    dhn_final_kernel<<<1, 256, 0, stream>>>(blockLoss, blockValid, blockQ, out);
}